// Round 8
// baseline (3440.467 us; speedup 1.0000x reference)
//
#include <hip/hip_runtime.h>
#include <cstdint>
#include <cstddef>

// R8 = R3 config (best, 370us) with per-kernel REPS amplification for
// rocprof attribution. All kernels are idempotent (pure functions of their
// inputs), so REPS>1 writes identical values -> absmax unchanged.
// True per-kernel time = dispatch_dur / REPS.
#define JAX_PARTITIONABLE 1

#define S_SCOPE 128   // SAMPLE_SCOPE
#define K_SAMP  10    // SAMPLE_NUM
#define F_DIM   602   // INPUT_DIM
#define H_DIM   256   // HIDDEN_DIM
#define O_DIM   41    // OUTPUT_DIM
#define BATCH_N 256

// ---------------- threefry2x32 (JAX-compatible, 20 rounds) ----------------
__host__ __device__ __forceinline__ void tf2x32(uint32_t k0, uint32_t k1,
                                                uint32_t x0, uint32_t x1,
                                                uint32_t* o0, uint32_t* o1) {
  uint32_t ks2 = k0 ^ k1 ^ 0x1BD11BDAu;
  x0 += k0; x1 += k1;
#define TF_R(d) { x0 += x1; x1 = (x1 << (d)) | (x1 >> (32 - (d))); x1 ^= x0; }
#define TF_G0 TF_R(13) TF_R(15) TF_R(26) TF_R(6)
#define TF_G1 TF_R(17) TF_R(29) TF_R(16) TF_R(24)
  TF_G0; x0 += k1;  x1 += ks2 + 1u;
  TF_G1; x0 += ks2; x1 += k0  + 2u;
  TF_G0; x0 += k0;  x1 += k1  + 3u;
  TF_G1; x0 += k1;  x1 += ks2 + 4u;
  TF_G0; x0 += ks2; x1 += k0  + 5u;
#undef TF_R
#undef TF_G0
#undef TF_G1
  *o0 = x0; *o1 = x1;
}

__device__ __forceinline__ float jax_gumbel(uint32_t ka, uint32_t kb, uint32_t j, uint32_t M) {
  uint32_t r0, r1, bits;
#if JAX_PARTITIONABLE
  tf2x32(ka, kb, 0u, j, &r0, &r1);
  bits = r0 ^ r1;
#else
  uint32_t half = M >> 1;
  if (j < half) { tf2x32(ka, kb, j, j + half, &r0, &r1); bits = r0; }
  else          { tf2x32(ka, kb, j - half, j, &r0, &r1); bits = r1; }
#endif
  float f = __uint_as_float((bits >> 9) | 0x3f800000u) - 1.0f;  // [0,1)
  if (f == 0.0f) f = 1.17549435e-38f;
  return -logf(-logf(f));
}

// ---------------- k_sg: g = ((feature[nodes] @ W) @ W^T), head per blockIdx.y ----
template<int R, int REPS>
__global__ void __launch_bounds__(256) k_sg(const float* __restrict__ feature,
                                            const float* __restrict__ Wa,
                                            const float* __restrict__ Wb,
                                            const int* __restrict__ nodes,
                                            float* __restrict__ g1,
                                            float* __restrict__ g2) {
  __shared__ __align__(16) float fl[R][604];
  __shared__ __align__(16) float sl[R][H_DIM];
  const float* __restrict__ W = blockIdx.y ? Wb : Wa;
  float* __restrict__ g = blockIdx.y ? g2 : g1;
  const int r0 = blockIdx.x * R;
  const int tid = threadIdx.x;
#pragma unroll 1
  for (int rep = 0; rep < REPS; ++rep) {
    __syncthreads();
    for (int r = 0; r < R; ++r) {
      const float* src = feature + (size_t)nodes[r0 + r] * F_DIM;
      for (int e = tid; e < 604; e += 256) fl[r][e] = (e < F_DIM) ? src[e] : 0.f;
    }
    __syncthreads();

    {
      const int h = tid;
      float a[R];
#pragma unroll
      for (int r = 0; r < R; ++r) a[r] = 0.f;
      for (int fc = 0; fc < 150; ++fc) {
        const int f = fc * 4;
        const float w0 = W[(size_t)(f + 0) * H_DIM + h];
        const float w1 = W[(size_t)(f + 1) * H_DIM + h];
        const float w2 = W[(size_t)(f + 2) * H_DIM + h];
        const float w3 = W[(size_t)(f + 3) * H_DIM + h];
#pragma unroll
        for (int r = 0; r < R; ++r) {
          const float4 v = *(const float4*)&fl[r][f];
          a[r] = fmaf(v.x, w0, a[r]); a[r] = fmaf(v.y, w1, a[r]);
          a[r] = fmaf(v.z, w2, a[r]); a[r] = fmaf(v.w, w3, a[r]);
        }
      }
      for (int f = 600; f < 602; ++f) {
        const float w = W[(size_t)f * H_DIM + h];
#pragma unroll
        for (int r = 0; r < R; ++r) a[r] = fmaf(fl[r][f], w, a[r]);
      }
#pragma unroll
      for (int r = 0; r < R; ++r) sl[r][h] = a[r];
    }
    __syncthreads();

    for (int j = 0; j < 3; ++j) {
      const int f = tid + j * 256;
      if (f < F_DIM) {
        const float4* wr = (const float4*)(W + (size_t)f * H_DIM);
        float b[R];
#pragma unroll
        for (int r = 0; r < R; ++r) b[r] = 0.f;
        for (int hq = 0; hq < H_DIM / 4; ++hq) {
          const float4 w = wr[hq];
#pragma unroll
          for (int r = 0; r < R; ++r) {
            const float4 v = *(const float4*)&sl[r][hq * 4];
            b[r] = fmaf(v.x, w.x, b[r]); b[r] = fmaf(v.y, w.y, b[r]);
            b[r] = fmaf(v.z, w.z, b[r]); b[r] = fmaf(v.w, w.w, b[r]);
          }
        }
#pragma unroll
        for (int r = 0; r < R; ++r)
          g[(size_t)(r0 + r) * F_DIM + f] = b[r];
      }
    }
  }
}

// ---------------- k_att: attention + sampling (+ fused layer-0 agg) ------------
template<int FUSE_Y, int BLK, int REPS>
__global__ void __launch_bounds__(BLK) k_att(const float* __restrict__ feature,
                                             const int* __restrict__ edge,
                                             const float* __restrict__ weight,
                                             const float* __restrict__ g1,
                                             const float* __restrict__ g2,
                                             const int* __restrict__ nodes,
                                             int n,
                                             const float* __restrict__ sample_a,
                                             uint32_t ska, uint32_t skb,
                                             float* __restrict__ adj_or_y,
                                             int* __restrict__ out_nodes) {
  constexpr int NW = BLK / 64;
  __shared__ __align__(16) float g1l[602];
  __shared__ __align__(16) float g2l[602];
  __shared__ float logitl[S_SCOPE];
  __shared__ float wtl[S_SCOPE];
  __shared__ int nbrl[S_SCOPE];
  __shared__ int coll[K_SAMP];
  __shared__ float selw[K_SAMP];
  __shared__ int selr[K_SAMP];

  const int nIdx = blockIdx.x;
  const int tid = threadIdx.x;
  const int lane = tid & 63;
  const int wave = tid >> 6;
  const int node = nodes[nIdx];

  const float a0v = sample_a[0], a1v = sample_a[1], a2v = sample_a[2];
  const float mx = fmaxf(a0v, fmaxf(a1v, a2v));
  const float e0 = expf(a0v - mx), e1 = expf(a1v - mx), e2 = expf(a2v - mx);
  const float inv = 1.0f / (e0 + e1 + e2);
  const float aw0 = e0 * inv, aw1 = e1 * inv, aw2 = e2 * inv;

#pragma unroll 1
  for (int rep = 0; rep < REPS; ++rep) {
    __syncthreads();
    for (int e = tid; e < F_DIM; e += BLK) {
      g1l[e] = g1[(size_t)nIdx * F_DIM + e];
      g2l[e] = g2[(size_t)nIdx * F_DIM + e];
    }
    __syncthreads();

    // phase 1: logits, 2 candidates in flight per wave, 10 batched loads
    for (int t16 = 0; t16 < S_SCOPE / (2 * NW); ++t16) {
      const int sA = wave + t16 * (2 * NW);
      const int sB = sA + NW;
      const int nbrA = edge[(size_t)node * S_SCOPE + sA];
      const int nbrB = edge[(size_t)node * S_SCOPE + sB];
      const float wtA = weight[(size_t)node * S_SCOPE + sA];
      const float wtB = weight[(size_t)node * S_SCOPE + sB];
      const float2* frA = (const float2*)(feature + (size_t)nbrA * F_DIM);
      const float2* frB = (const float2*)(feature + (size_t)nbrB * F_DIM);
      float2 vA[5], vB[5], gav[5], gbv[5];
#pragma unroll
      for (int t = 0; t < 5; ++t) {
        const int p = lane + t * 64;
        if (p < F_DIM / 2) {
          vA[t] = frA[p]; vB[t] = frB[p];
          gav[t] = ((const float2*)g1l)[p];
          gbv[t] = ((const float2*)g2l)[p];
        } else {
          vA[t] = make_float2(0.f, 0.f); vB[t] = make_float2(0.f, 0.f);
          gav[t] = make_float2(0.f, 0.f); gbv[t] = make_float2(0.f, 0.f);
        }
      }
      float d1A = 0.f, d2A = 0.f, d1B = 0.f, d2B = 0.f;
#pragma unroll
      for (int t = 0; t < 5; ++t) {
        d1A = fmaf(vA[t].x, gav[t].x, fmaf(vA[t].y, gav[t].y, d1A));
        d2A = fmaf(vA[t].x, gbv[t].x, fmaf(vA[t].y, gbv[t].y, d2A));
        d1B = fmaf(vB[t].x, gav[t].x, fmaf(vB[t].y, gav[t].y, d1B));
        d2B = fmaf(vB[t].x, gbv[t].x, fmaf(vB[t].y, gbv[t].y, d2B));
      }
#pragma unroll
      for (int off = 32; off > 0; off >>= 1) {
        d1A += __shfl_xor(d1A, off); d2A += __shfl_xor(d2A, off);
        d1B += __shfl_xor(d1B, off); d2B += __shfl_xor(d2B, off);
      }
      if (lane == 0) {
        const float attA = fmaxf(aw0 * d1A + aw1 * d2A + aw2 * wtA, 0.0f) + 1e-9f;
        const float attB = fmaxf(aw0 * d1B + aw1 * d2B + aw2 * wtB, 0.0f) + 1e-9f;
        logitl[sA] = logf(attA); wtl[sA] = wtA; nbrl[sA] = nbrA;
        logitl[sB] = logf(attB); wtl[sB] = wtB; nbrl[sB] = nbrB;
      }
    }
    __syncthreads();

    // phase 2: gumbel-argmax, one wave per draw
    const uint32_t M = (uint32_t)K_SAMP * (uint32_t)n * (uint32_t)S_SCOPE;
    for (int k = wave; k < K_SAMP; k += NW) {
      const uint32_t jbase = ((uint32_t)k * (uint32_t)n + (uint32_t)nIdx) * (uint32_t)S_SCOPE;
      float v0 = logitl[lane]      + jax_gumbel(ska, skb, jbase + (uint32_t)lane,        M);
      float v1 = logitl[lane + 64] + jax_gumbel(ska, skb, jbase + (uint32_t)(lane + 64), M);
      float best = v0; int bidx = lane;
      if (v1 > best) { best = v1; bidx = lane + 64; }
#pragma unroll
      for (int off = 1; off < 64; off <<= 1) {
        const float ov = __shfl_xor(best, off);
        const int oi = __shfl_xor(bidx, off);
        if (ov > best || (ov == best && oi < bidx)) { best = ov; bidx = oi; }
      }
      if (lane == 0) coll[k] = bidx;
    }
    __syncthreads();

    // phase 3
    if constexpr (FUSE_Y) {
      if (tid == 0) {
        float w[K_SAMP]; float sum = 0.f;
#pragma unroll
        for (int k = 0; k < K_SAMP; ++k) { w[k] = wtl[coll[k]]; sum += w[k]; }
        const float den = sum + 1e-9f;
#pragma unroll
        for (int k = 0; k < K_SAMP; ++k) {
          selw[k] = w[k] / den;
          selr[k] = nbrl[coll[k]];
        }
      }
      __syncthreads();
      for (int e = tid; e < F_DIM; e += BLK) {
        float acc = 0.f;
#pragma unroll
        for (int k = 0; k < K_SAMP; ++k)
          acc = fmaf(selw[k], feature[(size_t)selr[k] * F_DIM + e], acc);
        adj_or_y[(size_t)nIdx * F_DIM + e] = acc;
      }
    } else {
      if (tid == 0) {
        float w[K_SAMP]; float sum = 0.f;
#pragma unroll
        for (int k = 0; k < K_SAMP; ++k) { w[k] = wtl[coll[k]]; sum += w[k]; }
        const float den = sum + 1e-9f;
#pragma unroll
        for (int k = 0; k < K_SAMP; ++k) {
          adj_or_y[(size_t)nIdx * K_SAMP + k] = w[k] / den;
          out_nodes[nIdx * K_SAMP + k] = nbrl[coll[k]];
        }
      }
    }
  }
}

// ---------------- k_h: H = relu(y @ W1) ----------------
#define HROWS 4
template<int REPS>
__global__ void __launch_bounds__(256) k_h(const float* __restrict__ y,
                                           const float* __restrict__ W1,
                                           float* __restrict__ H) {
  __shared__ __align__(16) float yl[HROWS][604];
  const int r0 = blockIdx.x * HROWS;
  const int tid = threadIdx.x;
#pragma unroll 1
  for (int rep = 0; rep < REPS; ++rep) {
    __syncthreads();
    for (int r = 0; r < HROWS; ++r)
      for (int e = tid; e < 604; e += 256)
        yl[r][e] = (e < F_DIM) ? y[(size_t)(r0 + r) * F_DIM + e] : 0.f;
    __syncthreads();
    const int h = tid;
    float acc[HROWS];
#pragma unroll
    for (int r = 0; r < HROWS; ++r) acc[r] = 0.f;
    for (int fc = 0; fc < 150; ++fc) {
      const int f = fc * 4;
      const float w0 = W1[(size_t)(f + 0) * H_DIM + h];
      const float w1 = W1[(size_t)(f + 1) * H_DIM + h];
      const float w2 = W1[(size_t)(f + 2) * H_DIM + h];
      const float w3 = W1[(size_t)(f + 3) * H_DIM + h];
#pragma unroll
      for (int r = 0; r < HROWS; ++r) {
        const float4 v = *(const float4*)&yl[r][f];
        acc[r] = fmaf(v.x, w0, acc[r]); acc[r] = fmaf(v.y, w1, acc[r]);
        acc[r] = fmaf(v.z, w2, acc[r]); acc[r] = fmaf(v.w, w3, acc[r]);
      }
    }
    for (int f = 600; f < 602; ++f) {
      const float w = W1[(size_t)f * H_DIM + h];
#pragma unroll
      for (int r = 0; r < HROWS; ++r) acc[r] = fmaf(yl[r][f], w, acc[r]);
    }
#pragma unroll
    for (int r = 0; r < HROWS; ++r)
      H[(size_t)(r0 + r) * H_DIM + h] = fmaxf(acc[r], 0.f);
  }
}

// ---------------- k_final: out = (adj1-weighted sum of H) @ W2 ----------------
template<int REPS>
__global__ void __launch_bounds__(256) k_final(const float* __restrict__ H,
                                               const float* __restrict__ adj1,
                                               const float* __restrict__ W2,
                                               float* __restrict__ out) {
  __shared__ float zl[H_DIM];
  const int nIdx = blockIdx.x;
  const int tid = threadIdx.x;
#pragma unroll 1
  for (int rep = 0; rep < REPS; ++rep) {
    __syncthreads();
    float acc = 0.f;
#pragma unroll
    for (int k = 0; k < K_SAMP; ++k)
      acc = fmaf(adj1[(size_t)nIdx * K_SAMP + k],
                 H[(size_t)(nIdx * K_SAMP + k) * H_DIM + tid], acc);
    zl[tid] = acc;
    __syncthreads();
    if (tid < O_DIM) {
      float o = 0.f;
      for (int hh = 0; hh < H_DIM; ++hh)
        o = fmaf(zl[hh], W2[(size_t)hh * O_DIM + tid], o);
      out[(size_t)nIdx * O_DIM + tid] = o;
    }
  }
}

// ---------------- launch ----------------
extern "C" void kernel_launch(void* const* d_in, const int* in_sizes, int n_in,
                              void* d_out, int out_size, void* d_ws, size_t ws_size,
                              hipStream_t stream) {
  (void)in_sizes; (void)n_in; (void)out_size; (void)ws_size;
  const int*   ids       = (const int*)d_in[0];
  const float* feature   = (const float*)d_in[1];
  const int*   edge      = (const int*)d_in[2];
  const float* weight    = (const float*)d_in[3];
  const float* sample_W  = (const float*)d_in[4];
  const float* sample_W2 = (const float*)d_in[5];
  const float* sample_a  = (const float*)d_in[6];
  const float* W1        = (const float*)d_in[7];
  const float* W2        = (const float*)d_in[8];
  float* out = (float*)d_out;

  const int N1 = BATCH_N;           // 256
  const int N2 = BATCH_N * K_SAMP;  // 2560

  float* ws   = (float*)d_ws;
  float* g1   = ws;                                  // 2560*602
  float* g2   = g1 + (size_t)N2 * F_DIM;             // 2560*602
  float* yb   = g2 + (size_t)N2 * F_DIM;             // 2560*602
  float* Hb   = yb + (size_t)N2 * F_DIM;             // 2560*256
  float* adj1 = Hb + (size_t)N2 * H_DIM;             // 256*10
  int*   in1  = (int*)(adj1 + (size_t)N1 * K_SAMP);  // 2560

  // ---- JAX subkeys (host, deterministic) ----
  uint32_t k0 = 0u, k1 = 42u;
  uint32_t nk0, nk1, sk0a, sk0b, sk1a, sk1b;
#if JAX_PARTITIONABLE
  {
    tf2x32(k0, k1, 0u, 0u, &nk0, &nk1);
    tf2x32(k0, k1, 0u, 1u, &sk0a, &sk0b);
    tf2x32(nk0, nk1, 0u, 1u, &sk1a, &sk1b);
  }
#else
  {
    uint32_t a0, b0, a1, b1;
    tf2x32(k0, k1, 0u, 2u, &a0, &b0);
    tf2x32(k0, k1, 1u, 3u, &a1, &b1);
    nk0 = a0; nk1 = a1; sk0a = b0; sk0b = b1;
    tf2x32(nk0, nk1, 0u, 2u, &a0, &b0);
    tf2x32(nk0, nk1, 1u, 3u, &a1, &b1);
    sk1a = b0; sk1b = b1;
  }
#endif

  // ---- step 0 (frontier = ids, n = 256) ----  [amplified for attribution]
  k_sg<2, 30><<<dim3(N1 / 2, 2), 256, 0, stream>>>(feature, sample_W, sample_W2, ids, g1, g2);
  k_att<0, 1024, 14><<<N1, 1024, 0, stream>>>(feature, edge, weight, g1, g2, ids, N1,
                                              sample_a, sk0a, sk0b, adj1, in1);
  // ---- step 1 (frontier = in1, n = 2560) ----
  k_sg<10, 10><<<dim3(N2 / 10, 2), 256, 0, stream>>>(feature, sample_W, sample_W2, in1, g1, g2);
  k_att<1, 512, 4><<<N2, 512, 0, stream>>>(feature, edge, weight, g1, g2, in1, N2,
                                           sample_a, sk1a, sk1b, yb, nullptr);
  // ---- aggregation ----
  k_h<25><<<N2 / HROWS, 256, 0, stream>>>(yb, W1, Hb);
  k_final<60><<<N1, 256, 0, stream>>>(Hb, adj1, W2, out);
}

// Round 9
// 325.359 us; speedup vs baseline: 10.5744x; 10.5744x over previous
//
#include <hip/hip_runtime.h>
#include <cstdint>
#include <cstddef>

// R9 = R3 config with k_sg restructured to 512 threads/block (measured R8:
// k_sg was 129us at 23% occupancy, grid-limited to 2 blocks/CU; this doubles
// waves/CU at unchanged grid and W-traffic). All accumulation chains bitwise
// preserved (verified absmax 1.2e-4 rounds 1-8).
#define JAX_PARTITIONABLE 1

#define S_SCOPE 128   // SAMPLE_SCOPE
#define K_SAMP  10    // SAMPLE_NUM
#define F_DIM   602   // INPUT_DIM
#define H_DIM   256   // HIDDEN_DIM
#define O_DIM   41    // OUTPUT_DIM
#define BATCH_N 256

// ---------------- threefry2x32 (JAX-compatible, 20 rounds) ----------------
__host__ __device__ __forceinline__ void tf2x32(uint32_t k0, uint32_t k1,
                                                uint32_t x0, uint32_t x1,
                                                uint32_t* o0, uint32_t* o1) {
  uint32_t ks2 = k0 ^ k1 ^ 0x1BD11BDAu;
  x0 += k0; x1 += k1;
#define TF_R(d) { x0 += x1; x1 = (x1 << (d)) | (x1 >> (32 - (d))); x1 ^= x0; }
#define TF_G0 TF_R(13) TF_R(15) TF_R(26) TF_R(6)
#define TF_G1 TF_R(17) TF_R(29) TF_R(16) TF_R(24)
  TF_G0; x0 += k1;  x1 += ks2 + 1u;
  TF_G1; x0 += ks2; x1 += k0  + 2u;
  TF_G0; x0 += k0;  x1 += k1  + 3u;
  TF_G1; x0 += k1;  x1 += ks2 + 4u;
  TF_G0; x0 += ks2; x1 += k0  + 5u;
#undef TF_R
#undef TF_G0
#undef TF_G1
  *o0 = x0; *o1 = x1;
}

__device__ __forceinline__ float jax_gumbel(uint32_t ka, uint32_t kb, uint32_t j, uint32_t M) {
  uint32_t r0, r1, bits;
#if JAX_PARTITIONABLE
  tf2x32(ka, kb, 0u, j, &r0, &r1);
  bits = r0 ^ r1;
#else
  uint32_t half = M >> 1;
  if (j < half) { tf2x32(ka, kb, j, j + half, &r0, &r1); bits = r0; }
  else          { tf2x32(ka, kb, j - half, j, &r0, &r1); bits = r1; }
#endif
  float f = __uint_as_float((bits >> 9) | 0x3f800000u) - 1.0f;  // [0,1)
  if (f == 0.0f) f = 1.17549435e-38f;
  return -logf(-logf(f));
}

// ---------------- k_sg: g = ((feature[nodes] @ W) @ W^T), head per blockIdx.y ----
// 512 threads: phase A row-split between thread halves, phase B f-split over
// 512. Per-(row,h)/(row,f) chains identical to the 256-thread version.
template<int R>
__global__ void __launch_bounds__(512) k_sg(const float* __restrict__ feature,
                                            const float* __restrict__ Wa,
                                            const float* __restrict__ Wb,
                                            const int* __restrict__ nodes,
                                            float* __restrict__ g1,
                                            float* __restrict__ g2) {
  static_assert(R % 2 == 0, "R even");
  constexpr int RH = R / 2;
  __shared__ __align__(16) float fl[R][604];
  __shared__ __align__(16) float sl[R][H_DIM];
  const float* __restrict__ W = blockIdx.y ? Wb : Wa;
  float* __restrict__ g = blockIdx.y ? g2 : g1;
  const int r0 = blockIdx.x * R;
  const int tid = threadIdx.x;
  for (int r = 0; r < R; ++r) {
    const float* src = feature + (size_t)nodes[r0 + r] * F_DIM;
    for (int e = tid; e < 604; e += 512) fl[r][e] = (e < F_DIM) ? src[e] : 0.f;
  }
  __syncthreads();

  // phase A: s = x @ W. Thread half (tid>>8) owns RH rows; h = tid & 255.
  {
    const int rbase = (tid >> 8) * RH;
    const int h = tid & 255;
    float a[RH];
#pragma unroll
    for (int r = 0; r < RH; ++r) a[r] = 0.f;
    for (int fc = 0; fc < 150; ++fc) {
      const int f = fc * 4;
      const float w0 = W[(size_t)(f + 0) * H_DIM + h];
      const float w1 = W[(size_t)(f + 1) * H_DIM + h];
      const float w2 = W[(size_t)(f + 2) * H_DIM + h];
      const float w3 = W[(size_t)(f + 3) * H_DIM + h];
#pragma unroll
      for (int r = 0; r < RH; ++r) {
        const float4 v = *(const float4*)&fl[rbase + r][f];
        a[r] = fmaf(v.x, w0, a[r]); a[r] = fmaf(v.y, w1, a[r]);
        a[r] = fmaf(v.z, w2, a[r]); a[r] = fmaf(v.w, w3, a[r]);
      }
    }
    for (int f = 600; f < 602; ++f) {
      const float w = W[(size_t)f * H_DIM + h];
#pragma unroll
      for (int r = 0; r < RH; ++r) a[r] = fmaf(fl[rbase + r][f], w, a[r]);
    }
#pragma unroll
    for (int r = 0; r < RH; ++r) sl[rbase + r][h] = a[r];
  }
  __syncthreads();

  // phase B: g = s @ W^T. f = tid + 512j; each thread does all R rows.
  for (int j = 0; j < 2; ++j) {
    const int f = tid + j * 512;
    if (f < F_DIM) {
      const float4* wr = (const float4*)(W + (size_t)f * H_DIM);
      float b[R];
#pragma unroll
      for (int r = 0; r < R; ++r) b[r] = 0.f;
      for (int hq = 0; hq < H_DIM / 4; ++hq) {
        const float4 w = wr[hq];
#pragma unroll
        for (int r = 0; r < R; ++r) {
          const float4 v = *(const float4*)&sl[r][hq * 4];
          b[r] = fmaf(v.x, w.x, b[r]); b[r] = fmaf(v.y, w.y, b[r]);
          b[r] = fmaf(v.z, w.z, b[r]); b[r] = fmaf(v.w, w.w, b[r]);
        }
      }
#pragma unroll
      for (int r = 0; r < R; ++r)
        g[(size_t)(r0 + r) * F_DIM + f] = b[r];
    }
  }
}

// ---------------- k_att: attention + sampling (+ fused layer-0 agg) ------------
template<int FUSE_Y, int BLK>
__global__ void __launch_bounds__(BLK) k_att(const float* __restrict__ feature,
                                             const int* __restrict__ edge,
                                             const float* __restrict__ weight,
                                             const float* __restrict__ g1,
                                             const float* __restrict__ g2,
                                             const int* __restrict__ nodes,
                                             int n,
                                             const float* __restrict__ sample_a,
                                             uint32_t ska, uint32_t skb,
                                             float* __restrict__ adj_or_y,
                                             int* __restrict__ out_nodes) {
  constexpr int NW = BLK / 64;
  __shared__ __align__(16) float g1l[602];
  __shared__ __align__(16) float g2l[602];
  __shared__ float logitl[S_SCOPE];
  __shared__ float wtl[S_SCOPE];
  __shared__ int nbrl[S_SCOPE];
  __shared__ int coll[K_SAMP];
  __shared__ float selw[K_SAMP];
  __shared__ int selr[K_SAMP];

  const int nIdx = blockIdx.x;
  const int tid = threadIdx.x;
  const int lane = tid & 63;
  const int wave = tid >> 6;
  const int node = nodes[nIdx];

  const float a0v = sample_a[0], a1v = sample_a[1], a2v = sample_a[2];
  const float mx = fmaxf(a0v, fmaxf(a1v, a2v));
  const float e0 = expf(a0v - mx), e1 = expf(a1v - mx), e2 = expf(a2v - mx);
  const float inv = 1.0f / (e0 + e1 + e2);
  const float aw0 = e0 * inv, aw1 = e1 * inv, aw2 = e2 * inv;

  for (int e = tid; e < F_DIM; e += BLK) {
    g1l[e] = g1[(size_t)nIdx * F_DIM + e];
    g2l[e] = g2[(size_t)nIdx * F_DIM + e];
  }
  __syncthreads();

  // phase 1: logits, 2 candidates in flight per wave, 10 batched loads
  for (int t16 = 0; t16 < S_SCOPE / (2 * NW); ++t16) {
    const int sA = wave + t16 * (2 * NW);
    const int sB = sA + NW;
    const int nbrA = edge[(size_t)node * S_SCOPE + sA];
    const int nbrB = edge[(size_t)node * S_SCOPE + sB];
    const float wtA = weight[(size_t)node * S_SCOPE + sA];
    const float wtB = weight[(size_t)node * S_SCOPE + sB];
    const float2* frA = (const float2*)(feature + (size_t)nbrA * F_DIM);
    const float2* frB = (const float2*)(feature + (size_t)nbrB * F_DIM);
    float2 vA[5], vB[5], gav[5], gbv[5];
#pragma unroll
    for (int t = 0; t < 5; ++t) {
      const int p = lane + t * 64;
      if (p < F_DIM / 2) {
        vA[t] = frA[p]; vB[t] = frB[p];
        gav[t] = ((const float2*)g1l)[p];
        gbv[t] = ((const float2*)g2l)[p];
      } else {
        vA[t] = make_float2(0.f, 0.f); vB[t] = make_float2(0.f, 0.f);
        gav[t] = make_float2(0.f, 0.f); gbv[t] = make_float2(0.f, 0.f);
      }
    }
    float d1A = 0.f, d2A = 0.f, d1B = 0.f, d2B = 0.f;
#pragma unroll
    for (int t = 0; t < 5; ++t) {
      d1A = fmaf(vA[t].x, gav[t].x, fmaf(vA[t].y, gav[t].y, d1A));
      d2A = fmaf(vA[t].x, gbv[t].x, fmaf(vA[t].y, gbv[t].y, d2A));
      d1B = fmaf(vB[t].x, gav[t].x, fmaf(vB[t].y, gav[t].y, d1B));
      d2B = fmaf(vB[t].x, gbv[t].x, fmaf(vB[t].y, gbv[t].y, d2B));
    }
#pragma unroll
    for (int off = 32; off > 0; off >>= 1) {
      d1A += __shfl_xor(d1A, off); d2A += __shfl_xor(d2A, off);
      d1B += __shfl_xor(d1B, off); d2B += __shfl_xor(d2B, off);
    }
    if (lane == 0) {
      const float attA = fmaxf(aw0 * d1A + aw1 * d2A + aw2 * wtA, 0.0f) + 1e-9f;
      const float attB = fmaxf(aw0 * d1B + aw1 * d2B + aw2 * wtB, 0.0f) + 1e-9f;
      logitl[sA] = logf(attA); wtl[sA] = wtA; nbrl[sA] = nbrA;
      logitl[sB] = logf(attB); wtl[sB] = wtB; nbrl[sB] = nbrB;
    }
  }
  __syncthreads();

  // phase 2: gumbel-argmax, one wave per draw
  const uint32_t M = (uint32_t)K_SAMP * (uint32_t)n * (uint32_t)S_SCOPE;
  for (int k = wave; k < K_SAMP; k += NW) {
    const uint32_t jbase = ((uint32_t)k * (uint32_t)n + (uint32_t)nIdx) * (uint32_t)S_SCOPE;
    float v0 = logitl[lane]      + jax_gumbel(ska, skb, jbase + (uint32_t)lane,        M);
    float v1 = logitl[lane + 64] + jax_gumbel(ska, skb, jbase + (uint32_t)(lane + 64), M);
    float best = v0; int bidx = lane;
    if (v1 > best) { best = v1; bidx = lane + 64; }
#pragma unroll
    for (int off = 1; off < 64; off <<= 1) {
      const float ov = __shfl_xor(best, off);
      const int oi = __shfl_xor(bidx, off);
      if (ov > best || (ov == best && oi < bidx)) { best = ov; bidx = oi; }
    }
    if (lane == 0) coll[k] = bidx;
  }
  __syncthreads();

  // phase 3
  if constexpr (FUSE_Y) {
    if (tid == 0) {
      float w[K_SAMP]; float sum = 0.f;
#pragma unroll
      for (int k = 0; k < K_SAMP; ++k) { w[k] = wtl[coll[k]]; sum += w[k]; }
      const float den = sum + 1e-9f;
#pragma unroll
      for (int k = 0; k < K_SAMP; ++k) {
        selw[k] = w[k] / den;
        selr[k] = nbrl[coll[k]];
      }
    }
    __syncthreads();
    for (int e = tid; e < F_DIM; e += BLK) {
      float acc = 0.f;
#pragma unroll
      for (int k = 0; k < K_SAMP; ++k)
        acc = fmaf(selw[k], feature[(size_t)selr[k] * F_DIM + e], acc);
      adj_or_y[(size_t)nIdx * F_DIM + e] = acc;
    }
  } else {
    if (tid == 0) {
      float w[K_SAMP]; float sum = 0.f;
#pragma unroll
      for (int k = 0; k < K_SAMP; ++k) { w[k] = wtl[coll[k]]; sum += w[k]; }
      const float den = sum + 1e-9f;
#pragma unroll
      for (int k = 0; k < K_SAMP; ++k) {
        adj_or_y[(size_t)nIdx * K_SAMP + k] = w[k] / den;
        out_nodes[nIdx * K_SAMP + k] = nbrl[coll[k]];
      }
    }
  }
}

// ---------------- k_h: H = relu(y @ W1) ----------------
#define HROWS 4
__global__ void __launch_bounds__(256) k_h(const float* __restrict__ y,
                                           const float* __restrict__ W1,
                                           float* __restrict__ H) {
  __shared__ __align__(16) float yl[HROWS][604];
  const int r0 = blockIdx.x * HROWS;
  const int tid = threadIdx.x;
  for (int r = 0; r < HROWS; ++r)
    for (int e = tid; e < 604; e += 256)
      yl[r][e] = (e < F_DIM) ? y[(size_t)(r0 + r) * F_DIM + e] : 0.f;
  __syncthreads();
  const int h = tid;
  float acc[HROWS];
#pragma unroll
  for (int r = 0; r < HROWS; ++r) acc[r] = 0.f;
  for (int fc = 0; fc < 150; ++fc) {
    const int f = fc * 4;
    const float w0 = W1[(size_t)(f + 0) * H_DIM + h];
    const float w1 = W1[(size_t)(f + 1) * H_DIM + h];
    const float w2 = W1[(size_t)(f + 2) * H_DIM + h];
    const float w3 = W1[(size_t)(f + 3) * H_DIM + h];
#pragma unroll
    for (int r = 0; r < HROWS; ++r) {
      const float4 v = *(const float4*)&yl[r][f];
      acc[r] = fmaf(v.x, w0, acc[r]); acc[r] = fmaf(v.y, w1, acc[r]);
      acc[r] = fmaf(v.z, w2, acc[r]); acc[r] = fmaf(v.w, w3, acc[r]);
    }
  }
  for (int f = 600; f < 602; ++f) {
    const float w = W1[(size_t)f * H_DIM + h];
#pragma unroll
    for (int r = 0; r < HROWS; ++r) acc[r] = fmaf(yl[r][f], w, acc[r]);
  }
#pragma unroll
  for (int r = 0; r < HROWS; ++r)
    H[(size_t)(r0 + r) * H_DIM + h] = fmaxf(acc[r], 0.f);
}

// ---------------- k_final: out = (adj1-weighted sum of H) @ W2 ----------------
__global__ void __launch_bounds__(256) k_final(const float* __restrict__ H,
                                               const float* __restrict__ adj1,
                                               const float* __restrict__ W2,
                                               float* __restrict__ out) {
  __shared__ float zl[H_DIM];
  const int nIdx = blockIdx.x;
  const int tid = threadIdx.x;
  float acc = 0.f;
#pragma unroll
  for (int k = 0; k < K_SAMP; ++k)
    acc = fmaf(adj1[(size_t)nIdx * K_SAMP + k],
               H[(size_t)(nIdx * K_SAMP + k) * H_DIM + tid], acc);
  zl[tid] = acc;
  __syncthreads();
  if (tid < O_DIM) {
    float o = 0.f;
    for (int hh = 0; hh < H_DIM; ++hh)
      o = fmaf(zl[hh], W2[(size_t)hh * O_DIM + tid], o);
    out[(size_t)nIdx * O_DIM + tid] = o;
  }
}

// ---------------- launch ----------------
extern "C" void kernel_launch(void* const* d_in, const int* in_sizes, int n_in,
                              void* d_out, int out_size, void* d_ws, size_t ws_size,
                              hipStream_t stream) {
  (void)in_sizes; (void)n_in; (void)out_size; (void)ws_size;
  const int*   ids       = (const int*)d_in[0];
  const float* feature   = (const float*)d_in[1];
  const int*   edge      = (const int*)d_in[2];
  const float* weight    = (const float*)d_in[3];
  const float* sample_W  = (const float*)d_in[4];
  const float* sample_W2 = (const float*)d_in[5];
  const float* sample_a  = (const float*)d_in[6];
  const float* W1        = (const float*)d_in[7];
  const float* W2        = (const float*)d_in[8];
  float* out = (float*)d_out;

  const int N1 = BATCH_N;           // 256
  const int N2 = BATCH_N * K_SAMP;  // 2560

  float* ws   = (float*)d_ws;
  float* g1   = ws;                                  // 2560*602
  float* g2   = g1 + (size_t)N2 * F_DIM;             // 2560*602
  float* yb   = g2 + (size_t)N2 * F_DIM;             // 2560*602
  float* Hb   = yb + (size_t)N2 * F_DIM;             // 2560*256
  float* adj1 = Hb + (size_t)N2 * H_DIM;             // 256*10
  int*   in1  = (int*)(adj1 + (size_t)N1 * K_SAMP);  // 2560

  // ---- JAX subkeys (host, deterministic) ----
  uint32_t k0 = 0u, k1 = 42u;
  uint32_t nk0, nk1, sk0a, sk0b, sk1a, sk1b;
#if JAX_PARTITIONABLE
  {
    tf2x32(k0, k1, 0u, 0u, &nk0, &nk1);
    tf2x32(k0, k1, 0u, 1u, &sk0a, &sk0b);
    tf2x32(nk0, nk1, 0u, 1u, &sk1a, &sk1b);
  }
#else
  {
    uint32_t a0, b0, a1, b1;
    tf2x32(k0, k1, 0u, 2u, &a0, &b0);
    tf2x32(k0, k1, 1u, 3u, &a1, &b1);
    nk0 = a0; nk1 = a1; sk0a = b0; sk0b = b1;
    tf2x32(nk0, nk1, 0u, 2u, &a0, &b0);
    tf2x32(nk0, nk1, 1u, 3u, &a1, &b1);
    sk1a = b0; sk1b = b1;
  }
#endif

  // ---- step 0 (frontier = ids, n = 256) ----
  k_sg<2><<<dim3(N1 / 2, 2), 512, 0, stream>>>(feature, sample_W, sample_W2, ids, g1, g2);
  k_att<0, 1024><<<N1, 1024, 0, stream>>>(feature, edge, weight, g1, g2, ids, N1,
                                          sample_a, sk0a, sk0b, adj1, in1);
  // ---- step 1 (frontier = in1, n = 2560) ----
  k_sg<10><<<dim3(N2 / 10, 2), 512, 0, stream>>>(feature, sample_W, sample_W2, in1, g1, g2);
  k_att<1, 512><<<N2, 512, 0, stream>>>(feature, edge, weight, g1, g2, in1, N2,
                                        sample_a, sk1a, sk1b, yb, nullptr);
  // ---- aggregation ----
  k_h<<<N2 / HROWS, 256, 0, stream>>>(yb, W1, Hb);
  k_final<<<N1, 256, 0, stream>>>(Hb, adj1, W2, out);
}